// Round 15
// baseline (155.725 us; speedup 1.0000x reference)
//
#include <hip/hip_runtime.h>

// VersorRotorRNN: B=16, S=256, N=16, D=6, H=16, 32 blades (Cl(5,0)).
// Segmented parallel scan over S (SEGT=32, L=8), center split, and the
// full iso Cl(5,0) ≅ M2(H) ⊕ M2(H): eigenspaces in matrix-unit (x)
// quaternion coordinates. One GP = 2x(2x2 H-matmul) = 256 FMA. All basis
// changes folded into k_prep'd constants, derived constexpr from the
// Cayley sign fn and VERIFIED at compile time (static_assert).
//
// R2+R4+R11: never cap VGPR (no min-waves>=2, never >256-thr blocks).
// R5: no per-thread LDS weight reads -> wave-uniform scalar loads.
// R7/R8: never #pragma unroll the outer step loops (I$ bloat).
// R14: NEVER use device-scope fences/atomic-release in the hot path:
//   per-XCD L2s are non-coherent; 512 blocks x threadfence = L2 writeback
//   storm, k_fused 59.6 -> 150.9us. Launches are cheaper than coherence.
// R15: 3 -> 2 launches WITHOUT fences: k_prep inits out = x + b_out;
//   k_fused accumulates its 4-h partial sums into out via fire-and-forget
//   unsafeAtomicAdd (native global_atomic_add_f32, no return, no fence).
//   WS4 + k_reduce deleted. LP transposed -> bank-conflict-free.

#define EPS 1e-8f

constexpr int pcnt(int v) { int s = 0; while (v) { s += v & 1; v >>= 1; } return s; }
constexpr int sgni(int a, int b) {   // sign of e_a * e_b (Euclidean)
    a >>= 1; int s = 0;
    while (a) { s += pcnt(a & b); a >>= 1; }
    return (s & 1) ? -1 : 1;
}
struct El { int m; int s; };
constexpr El emul(El a, El b) { return { a.m ^ b.m, a.s * b.s * sgni(a.m, b.m) }; }

// Monomial basis of Cl_even(5,0): q_a * u^b * v^c with
//   g_i = e_i e_5 (i=0..3), q1=g0g1, q2=g1g2, q3=q1q2 (quaternions),
//   u = g0g1g2g3 (u^2=+1, commutes with q), v = g0g1g2 (v^2=+1, uv=-vu).
// Matrix rep: u=diag(1,-1), v=[[0,1],[1,0]] -> M2(R); algebra = H (x) M2(R).
struct MTab {
    int mm[16]; int ms[16];       // monomial idx (a + 4t) -> blade mask, sign
    int qi[4][4]; int qs[4][4];   // quaternion structure constants
    int sig[32];                  // sig[m] = sgn of omega-partner collapse
    bool ok;
};
constexpr MTab mkMT() {
    MTab t{}; t.ok = true;
    El g0{17,1}, g1{18,1}, g2{20,1}, g3{24,1};
    El q1 = emul(g0, g1), q2 = emul(g1, g2);
    El q[4] = { El{0,1}, q1, q2, emul(q1, q2) };
    El u = emul(emul(g0, g1), emul(g2, g3));
    El v = emul(emul(g0, g1), g2);
    El mset[4] = { El{0,1}, u, v, emul(u, v) };
    {   // compile-time algebra verification
        El c1 = emul(q[1], q[1]); if (!(c1.m == 0 && c1.s == -1)) t.ok = false;
        El c2 = emul(q[2], q[2]); if (!(c2.m == 0 && c2.s == -1)) t.ok = false;
        El c3 = emul(q[3], q[3]); if (!(c3.m == 0 && c3.s == -1)) t.ok = false;
        El c4 = emul(u, u); if (!(c4.m == 0 && c4.s == 1)) t.ok = false;
        El c5 = emul(v, v); if (!(c5.m == 0 && c5.s == 1)) t.ok = false;
        El c6 = emul(u, v), c7 = emul(v, u);
        if (!(c6.m == c7.m && c6.s == -c7.s)) t.ok = false;
        for (int i = 1; i < 4; ++i) {
            El a1 = emul(u, q[i]), a2 = emul(q[i], u);
            if (!(a1.m == a2.m && a1.s == a2.s)) t.ok = false;
            El b1 = emul(v, q[i]), b2 = emul(q[i], v);
            if (!(b1.m == b2.m && b1.s == b2.s)) t.ok = false;
        }
    }
    for (int tt = 0; tt < 4; ++tt)
        for (int a = 0; a < 4; ++a) {
            El e = emul(q[a], mset[tt]);
            t.mm[a + 4 * tt] = e.m; t.ms[a + 4 * tt] = e.s;
            if (pcnt(e.m) & 1) t.ok = false;
        }
    for (int i = 0; i < 16; ++i)
        for (int j = i + 1; j < 16; ++j)
            if (t.mm[i] == t.mm[j]) t.ok = false;
    for (int a = 0; a < 4; ++a)
        for (int b = 0; b < 4; ++b) {
            El e = emul(q[a], q[b]);
            int f = -1;
            for (int c = 0; c < 4; ++c) if (q[c].m == e.m) f = c;
            if (f < 0) { t.ok = false; f = 0; }
            t.qi[a][b] = f; t.qs[a][b] = e.s * q[f].s;
        }
    for (int m = 0; m < 32; ++m) t.sig[m] = sgni(m ^ 31, 31);
    return t;
}
__device__ constexpr MTab MT = mkMT();
static_assert(mkMT().ok, "Cl(5,0) = M2(H)+M2(H) derivation failed");

// ---- prep: transform W_in/b_in (and W_out recon) to matrix-unit coords,
//      AND initialize out = x + b_out (k_fused atomically accumulates). ----
// coord c16 = e*4 + a, entries e: 0=M11, 1=M12, 2=M21, 3=M22.
// WPm [h][es][ d*16+c | 96+c ] : 224 floats/h  (offset 0)
// OPm [h][es][ c*6+d ]         : 192 floats/h  (offset 3584)
__global__ __launch_bounds__(256, 1) void k_prep(
        const float* __restrict__ W_in, const float* __restrict__ b_in,
        const float* __restrict__ W_out, const float* __restrict__ x,
        const float* __restrict__ b_out, float* __restrict__ WP,
        float* __restrict__ out) {
    const int idx = blockIdx.x * 256 + threadIdx.x;
    if (idx < 393216) out[idx] = x[idx] + b_out[idx % 6];
    if (idx >= 6656) return;
    if (idx < 3584) {
        const int h = idx / 224, r = idx % 224;
        const int es = r / 112, r2 = r % 112;
        const float p = es ? -1.f : 1.f;
        const int c = (r2 < 96) ? (r2 & 15) : (r2 - 96);
        const int e = c >> 2, a = c & 3;
        const int base = (e == 0 || e == 3) ? 0 : 8;
        const float se = (e == 0 || e == 1) ? 1.f : -1.f;
        float val = 0.f;
        for (int k = 0; k < 2; ++k) {
            const int i = a + base + 4 * k;
            const float beta = k ? se : 1.f;
            const int m = MT.mm[i];
            const float s = (float)MT.ms[i];
            const float sg = (float)MT.sig[m];
            float wm, wn;
            if (r2 < 96) {
                const int d = r2 >> 4;
                wm = W_in[d * 512 + h * 32 + m];
                wn = W_in[d * 512 + h * 32 + (m ^ 31)];
            } else {
                wm = b_in[h * 32 + m];
                wn = b_in[h * 32 + (m ^ 31)];
            }
            val += beta * s * (wm + p * sg * wn);
        }
        WP[idx] = val;
    } else {
        const int j = idx - 3584;
        const int h = j / 192, r = j % 192;
        const int es = r / 96, r2 = r % 96;
        const float p = es ? -1.f : 1.f;
        const int c = r2 / 6, d = r2 % 6;
        const int e = c >> 2, a = c & 3;
        const int base = (e == 0 || e == 3) ? 0 : 8;
        const float se = (e == 0 || e == 1) ? 1.f : -1.f;
        float val = 0.f;
        for (int k = 0; k < 2; ++k) {
            const int i = a + base + 4 * k;
            const float beta = k ? se : 1.f;
            const int m = MT.mm[i];
            const float s = (float)MT.ms[i];
            const float sg = (float)MT.sig[m];
            const float wm = W_out[(h * 32 + m) * 6 + d];
            const float wn = W_out[(h * 32 + (m ^ 31)) * 6 + d];
            val += 0.25f * beta * s * (wm + p * sg * wn);
        }
        WP[idx] = val;
    }
}

// U = matrix coords of delta_r in one eigenspace (+identity I on M11_0,M22_0)
__device__ __forceinline__ void build16(const float* __restrict__ Wsp,
                                        const float xv[6], float U[16]) {
#pragma unroll
    for (int c = 0; c < 16; ++c) U[c] = Wsp[96 + c];
#pragma unroll
    for (int d = 0; d < 6; ++d)
#pragma unroll
        for (int c = 0; c < 16; ++c)
            U[c] = fmaf(xv[d], Wsp[d * 16 + c], U[c]);
    U[0]  += 1.0f;   // +1 scalar blade = identity matrix
    U[12] += 1.0f;
}

// z += p (*) q, quaternion product via constexpr structure constants
__device__ __forceinline__ void hfma(float* __restrict__ z,
                                     const float* __restrict__ p,
                                     const float* __restrict__ q) {
#pragma unroll
    for (int a = 0; a < 4; ++a)
#pragma unroll
        for (int b = 0; b < 4; ++b)
            z[MT.qi[a][b]] = fmaf((float)MT.qs[a][b] * p[a], q[b], z[MT.qi[a][b]]);
}

// Z = U * X as 2x2 quaternion matrices (U left). 128 FMA.
__device__ __forceinline__ void gpm(float* __restrict__ Z,
                                    const float* __restrict__ U,
                                    const float* __restrict__ X) {
#pragma unroll
    for (int k = 0; k < 16; ++k) Z[k] = 0.f;
    hfma(Z + 0,  U + 0, X + 0);   hfma(Z + 0,  U + 4,  X + 8);
    hfma(Z + 4,  U + 0, X + 4);   hfma(Z + 4,  U + 4,  X + 12);
    hfma(Z + 8,  U + 8, X + 0);   hfma(Z + 8,  U + 12, X + 8);
    hfma(Z + 12, U + 8, X + 4);   hfma(Z + 12, U + 12, X + 12);
}

__device__ __forceinline__ float ssum32(const float* a, const float* b) {
    float s0 = 0.f, s1 = 0.f, s2 = 0.f, s3 = 0.f;
#pragma unroll
    for (int k = 0; k < 16; k += 4) {
        s0 = fmaf(a[k],     a[k],     s0); s1 = fmaf(a[k + 1], a[k + 1], s1);
        s2 = fmaf(a[k + 2], a[k + 2], s2); s3 = fmaf(a[k + 3], a[k + 3], s3);
        s0 = fmaf(b[k],     b[k],     s0); s1 = fmaf(b[k + 1], b[k + 1], s1);
        s2 = fmaf(b[k + 2], b[k + 2], s2); s3 = fmaf(b[k + 3], b[k + 3], s3);
    }
    return (s0 + s1) + (s2 + s3);   // |psi|^2_blades = 0.25 * ssum32
}

// Block blk: waves w=0..3 -> h = 4*(blk&3)+w (same chain pair p = blk>>2).
// Lane: sc = lane&31 (segment), bn = p*2 + (lane>>5).
// Phase 4: block-local 4-h LDS reduce, then fire-and-forget float atomics
// into out (initialized to x + b_out by k_prep). No fences (R14 lesson).
__global__ __launch_bounds__(256, 1) void k_fused(
        const float* __restrict__ x, const float* __restrict__ WP,
        float* __restrict__ out) {
    __shared__ float LP[4 * 8 * 6 * 64];   // [(w*8+i)*6+d][lane], 48 KB

    const int tid  = threadIdx.x;
    const int lane = tid & 63;
    const int w    = __builtin_amdgcn_readfirstlane((int)(tid >> 6));
    const int hg   = blockIdx.x & 3;
    const int p    = blockIdx.x >> 2;
    const int h    = 4 * hg + w;
    const int sc   = lane & 31;
    const int bn = p * 2 + (lane >> 5), b = bn >> 4, n = bn & 15;
    const float* __restrict__ Wp0 = WP + h * 224;          // es+
    const float* __restrict__ Wp1 = WP + h * 224 + 112;    // es-
    const float* __restrict__ Op0 = WP + 3584 + h * 192;        // recon es+
    const float* __restrict__ Op1 = WP + 3584 + h * 192 + 96;   // recon es-

    // ---------- phase 1: segment product over t = sc*8 .. sc*8+7 ----------
    float Xp[16], Xm[16];
    {   // step 0: psi = u_0
        const int t = sc * 8;
        const float2* xp = (const float2*)(x + ((b * 256 + t) * 16 + n) * 6);
        float2 x01 = xp[0], x23 = xp[1], x45 = xp[2];
        const float xv[6] = {x01.x, x01.y, x23.x, x23.y, x45.x, x45.y};
        build16(Wp0, xv, Xp);
        build16(Wp1, xv, Xm);
    }
    for (int i = 1; i < 8; ++i) {
        const int t = sc * 8 + i;
        const float2* xp = (const float2*)(x + ((b * 256 + t) * 16 + n) * 6);
        float2 x01 = xp[0], x23 = xp[1], x45 = xp[2];
        const float xv[6] = {x01.x, x01.y, x23.x, x23.y, x45.x, x45.y};
        float U[16], Z[16];
        build16(Wp0, xv, U);
        gpm(Z, U, Xp);
#pragma unroll
        for (int k = 0; k < 16; ++k) Xp[k] = Z[k];
        build16(Wp1, xv, U);
        gpm(Z, U, Xm);
#pragma unroll
        for (int k = 0; k < 16; ++k) Xm[k] = Z[k];
    }
    {   // normalize once before the scan
        float rs = rsqrtf(0.25f * ssum32(Xp, Xm) + EPS);
#pragma unroll
        for (int k = 0; k < 16; ++k) { Xp[k] *= rs; Xm[k] *= rs; }
    }

    // ---------- phase 2: Kogge-Stone inclusive scan over sc (width 32) ----
#pragma unroll
    for (int k = 1; k < 32; k <<= 1) {
        float prp[16], prm[16];
#pragma unroll
        for (int j = 0; j < 16; ++j) {
            prp[j] = __shfl_up(Xp[j], k, 32);
            prm[j] = __shfl_up(Xm[j], k, 32);
        }
        if (sc >= k) {
            float Z[16];
            gpm(Z, Xp, prp);    // later range LEFT
#pragma unroll
            for (int m = 0; m < 16; ++m) Xp[m] = Z[m];
            gpm(Z, Xm, prm);
#pragma unroll
            for (int m = 0; m < 16; ++m) Xm[m] = Z[m];
        }
    }
    {   // single normalization of the inclusive prefix
        float rs = rsqrtf(0.25f * ssum32(Xp, Xm) + EPS);
#pragma unroll
        for (int j = 0; j < 16; ++j) { Xp[j] *= rs; Xm[j] *= rs; }
    }
    // exclusive shift by one
    float Rp[16], Rm[16];
#pragma unroll
    for (int j = 0; j < 16; ++j) {
        Rp[j] = __shfl_up(Xp[j], 1, 32);
        Rm[j] = __shfl_up(Xm[j], 1, 32);
    }
    if (sc == 0) {
#pragma unroll
        for (int j = 0; j < 16; ++j) { Rp[j] = 0.0f; Rm[j] = 0.0f; }
        Rp[0] = 1.0f; Rp[12] = 1.0f;   // identity matrix, both eigenspaces
        Rm[0] = 1.0f; Rm[12] = 1.0f;
    }

    // ---------- phase 3: apply interior + project -> LDS partials ----------
    for (int i = 0; i < 8; ++i) {
        const int t = sc * 8 + i;
        const float2* xp = (const float2*)(x + ((b * 256 + t) * 16 + n) * 6);
        float2 x01 = xp[0], x23 = xp[1], x45 = xp[2];
        const float xv[6] = {x01.x, x01.y, x23.x, x23.y, x45.x, x45.y};
        float U[16], Zp[16], Zm[16];
        build16(Wp0, xv, U);
        gpm(Zp, U, Rp);
        build16(Wp1, xv, U);
        gpm(Zm, U, Rm);
        float rs = rsqrtf(0.25f * ssum32(Zp, Zm) + EPS);
        float pd[6] = {0.f, 0.f, 0.f, 0.f, 0.f, 0.f};
#pragma unroll
        for (int c = 0; c < 16; ++c)
#pragma unroll
            for (int d = 0; d < 6; ++d) {
                pd[d] = fmaf(Zp[c], Op0[c * 6 + d], pd[d]);
                pd[d] = fmaf(Zm[c], Op1[c * 6 + d], pd[d]);
            }
#pragma unroll
        for (int k = 0; k < 16; ++k) { Rp[k] = Zp[k]; Rm[k] = Zm[k]; }
        // lane-contiguous LDS layout: conflict-free stores
        float* lp = LP + ((w * 8 + i) * 6) * 64 + lane;
#pragma unroll
        for (int d = 0; d < 6; ++d) lp[d * 64] = pd[d] * rs;
    }

    __syncthreads();

    // ---------- phase 4: 4-h LDS reduce + atomic accumulate into out ------
    // thread (w, lane) handles t = (lane&31)*8 + 2w + t1, c = lane>>5;
    // its LDS reads are at its own `lane` offset -> conflict-free.
    {
        const int c = lane >> 5;
        const int bn2 = p * 2 + c, b2 = bn2 >> 4, n2 = bn2 & 15;
        for (int t1 = 0; t1 < 2; ++t1) {
            const int i = 2 * w + t1;                 // t & 7
            const int t = ((lane & 31) << 3) + i;
            float* op = out + ((b2 * 256 + t) * 16 + n2) * 6;
#pragma unroll
            for (int d = 0; d < 6; ++d) {
                const int li = (i * 6 + d) * 64 + lane;
                float acc = LP[0 * 3072 + li] + LP[1 * 3072 + li]
                          + LP[2 * 3072 + li] + LP[3 * 3072 + li];
                unsafeAtomicAdd(op + d, acc);   // native global_atomic_add_f32
            }
        }
    }
}

extern "C" void kernel_launch(void* const* d_in, const int* in_sizes, int n_in,
                              void* d_out, int out_size, void* d_ws, size_t ws_size,
                              hipStream_t stream) {
    (void)in_sizes; (void)n_in; (void)out_size; (void)ws_size;
    const float* x     = (const float*)d_in[0];  // [16,256,16,6]
    const float* W_in  = (const float*)d_in[1];  // [6,512]
    const float* b_in  = (const float*)d_in[2];  // [512]
    const float* W_out = (const float*)d_in[3];  // [512,6]
    const float* b_out = (const float*)d_in[4];  // [6]
    float* out = (float*)d_out;                  // [16,256,16,6]

    float* WP = (float*)d_ws;                    // 6656 floats (26.6 KB)

    k_prep <<<1536, 256, 0, stream>>>(W_in, b_in, W_out, x, b_out, WP, out);
    k_fused<<<512,  256, 0, stream>>>(x, WP, out);
}

// Round 16
// 138.723 us; speedup vs baseline: 1.1226x; 1.1226x over previous
//
#include <hip/hip_runtime.h>

// VersorRotorRNN: B=16, S=256, N=16, D=6, H=16, 32 blades (Cl(5,0)).
// Segmented parallel scan over S (SEGT=32, L=8), center split, full iso
// Cl(5,0) ≅ M2(H) ⊕ M2(H): eigenspaces in matrix-unit (x) quaternion
// coordinates; one GP = 2x(2x2 H-matmul) = 256 FMA. R16: the basis change
// is applied ON THE FLY per step (raw scalar weight loads + constexpr-sign
// butterflies) so the prep kernel is deleted -> 2 dispatches total.
// The full build->recon pipeline is verified at compile time over all 32
// blade basis vectors (static_assert roundtrip == 4*identity).
//
// R2+R4+R11: never cap VGPR (no min-waves>=2, never >256-thr blocks).
// R5: no per-thread LDS weight reads -> wave-uniform scalar loads.
// R7/R8: never #pragma unroll the outer step loops (I$ bloat).
// R14: NEVER device-scope fences in hot path (per-XCD L2 writeback storm).
// R15: NEVER mass device atomics either (1.57M fabric atomics = +40us).
//   Cross-XCD communication of any kind loses to a plain kernel launch.
// R13 baseline: 119.4us = kernels ~69us + ~50us dispatch gaps (3 launches).

#define EPS 1e-8f

constexpr int pcnt(int v) { int s = 0; while (v) { s += v & 1; v >>= 1; } return s; }
constexpr int sgni(int a, int b) {   // sign of e_a * e_b (Euclidean)
    a >>= 1; int s = 0;
    while (a) { s += pcnt(a & b); a >>= 1; }
    return (s & 1) ? -1 : 1;
}
struct El { int m; int s; };
constexpr El emul(El a, El b) { return { a.m ^ b.m, a.s * b.s * sgni(a.m, b.m) }; }

// Monomial basis of Cl_even(5,0): q_a * u^b * v^c with
//   g_i = e_i e_5 (i=0..3), q1=g0g1, q2=g1g2, q3=q1q2 (quaternions),
//   u = g0g1g2g3 (u^2=+1, commutes with q), v = g0g1g2 (v^2=+1, uv=-vu).
// Matrix rep: u=diag(1,-1), v=[[0,1],[1,0]] -> M2(R); algebra = H (x) M2(R).
struct MTab {
    int mm[16]; int ms[16];       // monomial idx (a + 4t) -> blade mask, sign
    int qi[4][4]; int qs[4][4];   // quaternion structure constants
    int sig[32];                  // sig[m] = sgn of omega-partner collapse
    bool ok;
};
constexpr MTab mkMT() {
    MTab t{}; t.ok = true;
    El g0{17,1}, g1{18,1}, g2{20,1}, g3{24,1};
    El q1 = emul(g0, g1), q2 = emul(g1, g2);
    El q[4] = { El{0,1}, q1, q2, emul(q1, q2) };
    El u = emul(emul(g0, g1), emul(g2, g3));
    El v = emul(emul(g0, g1), g2);
    El mset[4] = { El{0,1}, u, v, emul(u, v) };
    {   // compile-time algebra verification
        El c1 = emul(q[1], q[1]); if (!(c1.m == 0 && c1.s == -1)) t.ok = false;
        El c2 = emul(q[2], q[2]); if (!(c2.m == 0 && c2.s == -1)) t.ok = false;
        El c3 = emul(q[3], q[3]); if (!(c3.m == 0 && c3.s == -1)) t.ok = false;
        El c4 = emul(u, u); if (!(c4.m == 0 && c4.s == 1)) t.ok = false;
        El c5 = emul(v, v); if (!(c5.m == 0 && c5.s == 1)) t.ok = false;
        El c6 = emul(u, v), c7 = emul(v, u);
        if (!(c6.m == c7.m && c6.s == -c7.s)) t.ok = false;
        for (int i = 1; i < 4; ++i) {
            El a1 = emul(u, q[i]), a2 = emul(q[i], u);
            if (!(a1.m == a2.m && a1.s == a2.s)) t.ok = false;
            El b1 = emul(v, q[i]), b2 = emul(q[i], v);
            if (!(b1.m == b2.m && b1.s == b2.s)) t.ok = false;
        }
    }
    for (int tt = 0; tt < 4; ++tt)
        for (int a = 0; a < 4; ++a) {
            El e = emul(q[a], mset[tt]);
            t.mm[a + 4 * tt] = e.m; t.ms[a + 4 * tt] = e.s;
            if (pcnt(e.m) & 1) t.ok = false;
        }
    for (int i = 0; i < 16; ++i)
        for (int j = i + 1; j < 16; ++j)
            if (t.mm[i] == t.mm[j]) t.ok = false;
    for (int a = 0; a < 4; ++a)
        for (int b = 0; b < 4; ++b) {
            El e = emul(q[a], q[b]);
            int f = -1;
            for (int c = 0; c < 4; ++c) if (q[c].m == e.m) f = c;
            if (f < 0) { t.ok = false; f = 0; }
            t.qi[a][b] = f; t.qs[a][b] = e.s * q[f].s;
        }
    for (int m = 0; m < 32; ++m) t.sig[m] = sgni(m ^ 31, 31);
    return t;
}
__device__ constexpr MTab MT = mkMT();
static_assert(mkMT().ok, "Cl(5,0) = M2(H)+M2(H) derivation failed");

// ---- on-the-fly transform tables ----
// Forward (blade V -> matrix coords U±), coord c16 = e*4+a:
//   U±[c] = F0 V[M0] ± G0 V[M0^31] + F1 V[M1] ± G1 V[M1^31]
// Inverse (matrix Z± -> blade coords, x4 scale folded into rs):
//   i = a+4t: cp = Z[E1*4+a] + SSG*Z[E2*4+a];  ev=RS(cp+cm); od=RSX(cp-cm)
//   blade[RM[i]] += ev ; blade[RM[i]^31] += od
struct VTab {
    int M0[16], M0X[16], M1[16], M1X[16];
    float F0[16], G0[16], F1[16], G1[16];
    int RM[16], RMX[16];
    float RS[16], RSX[16];
};
constexpr VTab mkVT() {
    VTab t{};
    MTab mt = mkMT();
    for (int c = 0; c < 16; ++c) {
        int e = c >> 2, a = c & 3;
        int base = (e == 0 || e == 3) ? 0 : 8;
        int se = (e == 0 || e == 1) ? 1 : -1;
        int i0 = a + base, i1 = i0 + 4;
        t.M0[c] = mt.mm[i0]; t.M0X[c] = mt.mm[i0] ^ 31;
        t.M1[c] = mt.mm[i1]; t.M1X[c] = mt.mm[i1] ^ 31;
        t.F0[c] = (float)mt.ms[i0];
        t.G0[c] = (float)(mt.ms[i0] * mt.sig[mt.mm[i0]]);
        t.F1[c] = (float)(se * mt.ms[i1]);
        t.G1[c] = (float)(se * mt.ms[i1] * mt.sig[mt.mm[i1]]);
    }
    for (int i = 0; i < 16; ++i) {
        t.RM[i] = mt.mm[i]; t.RMX[i] = mt.mm[i] ^ 31;
        t.RS[i] = (float)mt.ms[i];
        t.RSX[i] = (float)(mt.sig[mt.mm[i]] * mt.ms[i]);
    }
    return t;
}
__device__ constexpr VTab VT = mkVT();

// Compile-time roundtrip verification of the EXACT runtime pipeline:
// forward butterfly then inverse butterfly over each blade basis vector
// must give 4*identity (integer arithmetic, ground truth = delta).
constexpr bool verifyVT() {
    MTab mt = mkMT();
    for (int m = 0; m < 32; ++m) {
        int V[32] = {}; V[m] = 1;
        int Up[16] = {}, Um[16] = {};
        for (int c = 0; c < 16; ++c) {
            int e = c >> 2, a = c & 3;
            int base = (e == 0 || e == 3) ? 0 : 8;
            int se = (e == 0 || e == 1) ? 1 : -1;
            int i0 = a + base, i1 = i0 + 4;
            int m0 = mt.mm[i0], m1 = mt.mm[i1];
            int f0 = mt.ms[i0], g0 = f0 * mt.sig[m0];
            int f1 = se * mt.ms[i1], g1 = f1 * mt.sig[m1];
            int a0 = f0 * V[m0], b0 = g0 * V[m0 ^ 31];
            int a1 = f1 * V[m1], b1 = g1 * V[m1 ^ 31];
            Up[c] = a0 + b0 + a1 + b1;
            Um[c] = a0 - b0 + a1 - b1;
        }
        int r4[32] = {};
        for (int i = 0; i < 16; ++i) {
            int tt = i >> 2, a = i & 3;
            int e1 = (tt < 2) ? 0 : 1, e2 = (tt < 2) ? 3 : 2;
            int sg = (tt == 1 || tt == 3) ? -1 : 1;
            int cp = Up[e1 * 4 + a] + sg * Up[e2 * 4 + a];
            int cm = Um[e1 * 4 + a] + sg * Um[e2 * 4 + a];
            int ev = cp + cm, od = cp - cm;
            r4[mt.mm[i]] += mt.ms[i] * ev;
            r4[mt.mm[i] ^ 31] += mt.sig[mt.mm[i]] * mt.ms[i] * od;
        }
        for (int k = 0; k < 32; ++k)
            if (r4[k] != (k == m ? 4 : 0)) return false;
    }
    return true;
}
static_assert(verifyVT(), "on-the-fly eigen-transform roundtrip failed");

// U± = matrix coords of delta_r from RAW weights (scalar, wave-uniform h).
// V = b_in[h] + x.W_in[:,h*32+..] (+1 scalar), then constexpr-sign butterfly.
__device__ __forceinline__ void build_es(const float* __restrict__ Wh,
                                         const float* __restrict__ Bh,
                                         const float xv[6],
                                         float Up[16], float Um[16]) {
    float V[32];
#pragma unroll
    for (int m = 0; m < 32; ++m) V[m] = Bh[m];
#pragma unroll
    for (int d = 0; d < 6; ++d)
#pragma unroll
        for (int m = 0; m < 32; ++m)
            V[m] = fmaf(xv[d], Wh[d * 512 + m], V[m]);
    V[0] += 1.0f;  // delta_r's +1 (scalar blade)
#pragma unroll
    for (int c = 0; c < 16; ++c) {
        const float a0 = VT.F0[c] * V[VT.M0[c]], b0 = VT.G0[c] * V[VT.M0X[c]];
        const float a1 = VT.F1[c] * V[VT.M1[c]], b1 = VT.G1[c] * V[VT.M1X[c]];
        Up[c] = (a0 + b0) + (a1 + b1);
        Um[c] = (a0 - b0) + (a1 - b1);
    }
}

// z += p (*) q, quaternion product via constexpr structure constants
__device__ __forceinline__ void hfma(float* __restrict__ z,
                                     const float* __restrict__ p,
                                     const float* __restrict__ q) {
#pragma unroll
    for (int a = 0; a < 4; ++a)
#pragma unroll
        for (int b = 0; b < 4; ++b)
            z[MT.qi[a][b]] = fmaf((float)MT.qs[a][b] * p[a], q[b], z[MT.qi[a][b]]);
}

// Z = U * X as 2x2 quaternion matrices (U left). 128 FMA.
__device__ __forceinline__ void gpm(float* __restrict__ Z,
                                    const float* __restrict__ U,
                                    const float* __restrict__ X) {
#pragma unroll
    for (int k = 0; k < 16; ++k) Z[k] = 0.f;
    hfma(Z + 0,  U + 0, X + 0);   hfma(Z + 0,  U + 4,  X + 8);
    hfma(Z + 4,  U + 0, X + 4);   hfma(Z + 4,  U + 4,  X + 12);
    hfma(Z + 8,  U + 8, X + 0);   hfma(Z + 8,  U + 12, X + 8);
    hfma(Z + 12, U + 8, X + 4);   hfma(Z + 12, U + 12, X + 12);
}

__device__ __forceinline__ float ssum32(const float* a, const float* b) {
    float s0 = 0.f, s1 = 0.f, s2 = 0.f, s3 = 0.f;
#pragma unroll
    for (int k = 0; k < 16; k += 4) {
        s0 = fmaf(a[k],     a[k],     s0); s1 = fmaf(a[k + 1], a[k + 1], s1);
        s2 = fmaf(a[k + 2], a[k + 2], s2); s3 = fmaf(a[k + 3], a[k + 3], s3);
        s0 = fmaf(b[k],     b[k],     s0); s1 = fmaf(b[k + 1], b[k + 1], s1);
        s2 = fmaf(b[k + 2], b[k + 2], s2); s3 = fmaf(b[k + 3], b[k + 3], s3);
    }
    return (s0 + s1) + (s2 + s3);   // |psi|^2_blades = 0.25 * ssum32
}

// Block blk: waves w=0..3 -> h = 4*(blk&3)+w (same chain pair p = blk>>2).
// Lane: sc = lane&31 (segment), bn = p*2 + (lane>>5).
__global__ __launch_bounds__(256, 1) void k_fused(
        const float* __restrict__ x, const float* __restrict__ W_in,
        const float* __restrict__ b_in, const float* __restrict__ W_out,
        float* __restrict__ WS4) {
    __shared__ float LP[4 * 8 * 64 * 6];   // [w][i][lane][d], 48 KB

    const int tid  = threadIdx.x;
    const int lane = tid & 63;
    const int w    = __builtin_amdgcn_readfirstlane((int)(tid >> 6));
    const int hg   = blockIdx.x & 3;
    const int p    = blockIdx.x >> 2;
    const int h    = 4 * hg + w;
    const int sc   = lane & 31;
    const int bn = p * 2 + (lane >> 5), b = bn >> 4, n = bn & 15;
    const float* __restrict__ Wh = W_in  + h * 32;    // [d*512 + m]
    const float* __restrict__ Bh = b_in  + h * 32;    // [m]
    const float* __restrict__ Wo = W_out + h * 192;   // [m*6 + d]

    // ---------- phase 1: segment product over t = sc*8 .. sc*8+7 ----------
    float Xp[16], Xm[16];
    {   // step 0: psi = u_0
        const int t = sc * 8;
        const float2* xp = (const float2*)(x + ((b * 256 + t) * 16 + n) * 6);
        float2 x01 = xp[0], x23 = xp[1], x45 = xp[2];
        const float xv[6] = {x01.x, x01.y, x23.x, x23.y, x45.x, x45.y};
        build_es(Wh, Bh, xv, Xp, Xm);
    }
    for (int i = 1; i < 8; ++i) {
        const int t = sc * 8 + i;
        const float2* xp = (const float2*)(x + ((b * 256 + t) * 16 + n) * 6);
        float2 x01 = xp[0], x23 = xp[1], x45 = xp[2];
        const float xv[6] = {x01.x, x01.y, x23.x, x23.y, x45.x, x45.y};
        float Up[16], Um[16], Z[16];
        build_es(Wh, Bh, xv, Up, Um);
        gpm(Z, Up, Xp);
#pragma unroll
        for (int k = 0; k < 16; ++k) Xp[k] = Z[k];
        gpm(Z, Um, Xm);
#pragma unroll
        for (int k = 0; k < 16; ++k) Xm[k] = Z[k];
    }
    {   // normalize once before the scan
        float rs = rsqrtf(0.25f * ssum32(Xp, Xm) + EPS);
#pragma unroll
        for (int k = 0; k < 16; ++k) { Xp[k] *= rs; Xm[k] *= rs; }
    }

    // ---------- phase 2: Kogge-Stone inclusive scan over sc (width 32) ----
#pragma unroll
    for (int k = 1; k < 32; k <<= 1) {
        float prp[16], prm[16];
#pragma unroll
        for (int j = 0; j < 16; ++j) {
            prp[j] = __shfl_up(Xp[j], k, 32);
            prm[j] = __shfl_up(Xm[j], k, 32);
        }
        if (sc >= k) {
            float Z[16];
            gpm(Z, Xp, prp);    // later range LEFT
#pragma unroll
            for (int m = 0; m < 16; ++m) Xp[m] = Z[m];
            gpm(Z, Xm, prm);
#pragma unroll
            for (int m = 0; m < 16; ++m) Xm[m] = Z[m];
        }
    }
    {   // single normalization of the inclusive prefix
        float rs = rsqrtf(0.25f * ssum32(Xp, Xm) + EPS);
#pragma unroll
        for (int j = 0; j < 16; ++j) { Xp[j] *= rs; Xm[j] *= rs; }
    }
    // exclusive shift by one
    float Rp[16], Rm[16];
#pragma unroll
    for (int j = 0; j < 16; ++j) {
        Rp[j] = __shfl_up(Xp[j], 1, 32);
        Rm[j] = __shfl_up(Xm[j], 1, 32);
    }
    if (sc == 0) {
#pragma unroll
        for (int j = 0; j < 16; ++j) { Rp[j] = 0.0f; Rm[j] = 0.0f; }
        Rp[0] = 1.0f; Rp[12] = 1.0f;   // identity matrix, both eigenspaces
        Rm[0] = 1.0f; Rm[12] = 1.0f;
    }

    // ---------- phase 3: apply interior + project -> LDS partials ----------
    for (int i = 0; i < 8; ++i) {
        const int t = sc * 8 + i;
        const float2* xp = (const float2*)(x + ((b * 256 + t) * 16 + n) * 6);
        float2 x01 = xp[0], x23 = xp[1], x45 = xp[2];
        const float xv[6] = {x01.x, x01.y, x23.x, x23.y, x45.x, x45.y};
        float Up[16], Um[16], Zp[16], Zm[16];
        build_es(Wh, Bh, xv, Up, Um);
        gpm(Zp, Up, Rp);
        gpm(Zm, Um, Rm);
        // 0.25 matrix->blade scale folded into rs
        float rs = 0.25f * rsqrtf(0.25f * ssum32(Zp, Zm) + EPS);
        float pd[6] = {0.f, 0.f, 0.f, 0.f, 0.f, 0.f};
#pragma unroll
        for (int i16 = 0; i16 < 16; ++i16) {
            const int tt = i16 >> 2, a = i16 & 3;
            const int e1 = (tt < 2) ? 0 : 1, e2 = (tt < 2) ? 3 : 2;
            const float sg = (tt == 1 || tt == 3) ? -1.f : 1.f;
            const float cp = Zp[e1 * 4 + a] + sg * Zp[e2 * 4 + a];
            const float cm = Zm[e1 * 4 + a] + sg * Zm[e2 * 4 + a];
            const float ev = VT.RS[i16]  * (cp + cm);
            const float od = VT.RSX[i16] * (cp - cm);
            const float* wm = Wo + VT.RM[i16]  * 6;
            const float* wx = Wo + VT.RMX[i16] * 6;
#pragma unroll
            for (int d = 0; d < 6; ++d) {
                pd[d] = fmaf(ev, wm[d], pd[d]);
                pd[d] = fmaf(od, wx[d], pd[d]);
            }
        }
#pragma unroll
        for (int k = 0; k < 16; ++k) { Rp[k] = Zp[k]; Rm[k] = Zm[k]; }
        float* lp = LP + ((w * 8 + i) * 64 + lane) * 6;
#pragma unroll
        for (int d = 0; d < 6; ++d) lp[d] = pd[d] * rs;
    }

    __syncthreads();

    // ---------- phase 4: reduce the block's 4 h, coalesced WS4 write ------
    float* outp = WS4 + (hg * 128 + p) * 3072;
    for (int s = tid; s < 3072; s += 256) {
        const int d = s % 6, tc = s / 6;
        const int c = tc & 1, t = tc >> 1;
        const int li = ((t & 7) * 64 + (c * 32 + (t >> 3))) * 6 + d;
        float acc = LP[0 * 3072 + li] + LP[1 * 3072 + li]
                  + LP[2 * 3072 + li] + LP[3 * 3072 + li];
        outp[s] = acc;
    }
}

// out[o] = x[o] + b_out[d] + sum_hg WS4[hg][p][slot]
__global__ __launch_bounds__(256, 1) void k_reduce(
        const float* __restrict__ x, const float* __restrict__ b_out,
        const float* __restrict__ WS4, float* __restrict__ out) {
    const int idx = blockIdx.x * 256 + threadIdx.x;  // 393216 total
    const int p = idx / 3072, s = idx % 3072;
    const int d = s % 6, tc = s / 6;
    const int c = tc & 1, t = tc >> 1;
    const int bn = p * 2 + c, b = bn >> 4, n = bn & 15;
    const int o = ((b * 256 + t) * 16 + n) * 6 + d;
    float acc = x[o] + b_out[d];
#pragma unroll
    for (int hg = 0; hg < 4; ++hg)
        acc += WS4[(hg * 128 + p) * 3072 + s];
    out[o] = acc;
}

extern "C" void kernel_launch(void* const* d_in, const int* in_sizes, int n_in,
                              void* d_out, int out_size, void* d_ws, size_t ws_size,
                              hipStream_t stream) {
    (void)in_sizes; (void)n_in; (void)out_size; (void)ws_size;
    const float* x     = (const float*)d_in[0];  // [16,256,16,6]
    const float* W_in  = (const float*)d_in[1];  // [6,512]
    const float* b_in  = (const float*)d_in[2];  // [512]
    const float* W_out = (const float*)d_in[3];  // [512,6]
    const float* b_out = (const float*)d_in[4];  // [6]
    float* out = (float*)d_out;                  // [16,256,16,6]

    float* WS4 = (float*)d_ws;                   // 4*128*3072 floats (6 MB)

    k_fused <<<512,  256, 0, stream>>>(x, W_in, b_in, W_out, WS4);
    k_reduce<<<1536, 256, 0, stream>>>(x, b_out, WS4, out);
}

// Round 17
// 126.607 us; speedup vs baseline: 1.2300x; 1.0957x over previous
//
#include <hip/hip_runtime.h>

// VersorRotorRNN: B=16, S=256, N=16, D=6, H=16, 32 blades (Cl(5,0)).
// Segmented parallel scan over S (SEGT=64, L=4), center split, full iso
// Cl(5,0) ≅ M2(H) ⊕ M2(H): eigenspaces in matrix-unit (x) quaternion
// coordinates; one GP = 2x(2x2 H-matmul) = 256 FMA. Basis changes folded
// into k_prep'd constants (constexpr-derived, compile-time verified).
//
// R2+R4+R11: never cap VGPR (no min-waves>=2, never >256-thr blocks).
// R5: no per-thread LDS weight reads -> wave-uniform scalar loads.
// R7/R8: never #pragma unroll the outer step loops (I$ bloat).
// R14/R15/R16: launch-reduction all lost more kernel time than the ~2-4us
//   a dispatch costs (fences=L2 storm, atomics=fabric, on-the-fly=+38%
//   VALU). Keep R13's 3-launch structure.
// R17: SEGT 32->64 on the R13 structure: wave = ONE chain (scan width 64,
//   6 rounds), block = 4h x 1 chain, grid 1024 = 4 blocks/CU (16 waves/CU,
//   occupancy 17->33%). L=4 halves LDS to 24 KB. Work +19%, issue +~20%.

#define EPS 1e-8f

constexpr int pcnt(int v) { int s = 0; while (v) { s += v & 1; v >>= 1; } return s; }
constexpr int sgni(int a, int b) {   // sign of e_a * e_b (Euclidean)
    a >>= 1; int s = 0;
    while (a) { s += pcnt(a & b); a >>= 1; }
    return (s & 1) ? -1 : 1;
}
struct El { int m; int s; };
constexpr El emul(El a, El b) { return { a.m ^ b.m, a.s * b.s * sgni(a.m, b.m) }; }

// Monomial basis of Cl_even(5,0): q_a * u^b * v^c with
//   g_i = e_i e_5 (i=0..3), q1=g0g1, q2=g1g2, q3=q1q2 (quaternions),
//   u = g0g1g2g3 (u^2=+1, commutes with q), v = g0g1g2 (v^2=+1, uv=-vu).
// Matrix rep: u=diag(1,-1), v=[[0,1],[1,0]] -> M2(R); algebra = H (x) M2(R).
struct MTab {
    int mm[16]; int ms[16];       // monomial idx (a + 4t) -> blade mask, sign
    int qi[4][4]; int qs[4][4];   // quaternion structure constants
    int sig[32];                  // sig[m] = sgn of omega-partner collapse
    bool ok;
};
constexpr MTab mkMT() {
    MTab t{}; t.ok = true;
    El g0{17,1}, g1{18,1}, g2{20,1}, g3{24,1};
    El q1 = emul(g0, g1), q2 = emul(g1, g2);
    El q[4] = { El{0,1}, q1, q2, emul(q1, q2) };
    El u = emul(emul(g0, g1), emul(g2, g3));
    El v = emul(emul(g0, g1), g2);
    El mset[4] = { El{0,1}, u, v, emul(u, v) };
    {   // compile-time algebra verification
        El c1 = emul(q[1], q[1]); if (!(c1.m == 0 && c1.s == -1)) t.ok = false;
        El c2 = emul(q[2], q[2]); if (!(c2.m == 0 && c2.s == -1)) t.ok = false;
        El c3 = emul(q[3], q[3]); if (!(c3.m == 0 && c3.s == -1)) t.ok = false;
        El c4 = emul(u, u); if (!(c4.m == 0 && c4.s == 1)) t.ok = false;
        El c5 = emul(v, v); if (!(c5.m == 0 && c5.s == 1)) t.ok = false;
        El c6 = emul(u, v), c7 = emul(v, u);
        if (!(c6.m == c7.m && c6.s == -c7.s)) t.ok = false;
        for (int i = 1; i < 4; ++i) {
            El a1 = emul(u, q[i]), a2 = emul(q[i], u);
            if (!(a1.m == a2.m && a1.s == a2.s)) t.ok = false;
            El b1 = emul(v, q[i]), b2 = emul(q[i], v);
            if (!(b1.m == b2.m && b1.s == b2.s)) t.ok = false;
        }
    }
    for (int tt = 0; tt < 4; ++tt)
        for (int a = 0; a < 4; ++a) {
            El e = emul(q[a], mset[tt]);
            t.mm[a + 4 * tt] = e.m; t.ms[a + 4 * tt] = e.s;
            if (pcnt(e.m) & 1) t.ok = false;
        }
    for (int i = 0; i < 16; ++i)
        for (int j = i + 1; j < 16; ++j)
            if (t.mm[i] == t.mm[j]) t.ok = false;
    for (int a = 0; a < 4; ++a)
        for (int b = 0; b < 4; ++b) {
            El e = emul(q[a], q[b]);
            int f = -1;
            for (int c = 0; c < 4; ++c) if (q[c].m == e.m) f = c;
            if (f < 0) { t.ok = false; f = 0; }
            t.qi[a][b] = f; t.qs[a][b] = e.s * q[f].s;
        }
    for (int m = 0; m < 32; ++m) t.sig[m] = sgni(m ^ 31, 31);
    return t;
}
__device__ constexpr MTab MT = mkMT();
static_assert(mkMT().ok, "Cl(5,0) = M2(H)+M2(H) derivation failed");

// ---- prep: transform W_in/b_in (and W_out recon) to matrix-unit coords ----
// coord c16 = e*4 + a, entries e: 0=M11, 1=M12, 2=M21, 3=M22.
// WPm [h][es][ d*16+c | 96+c ] : 224 floats/h  (offset 0)
// OPm [h][es][ c*6+d ]         : 192 floats/h  (offset 3584)
__global__ __launch_bounds__(256, 1) void k_prep(
        const float* __restrict__ W_in, const float* __restrict__ b_in,
        const float* __restrict__ W_out, float* __restrict__ WP) {
    const int idx = blockIdx.x * 256 + threadIdx.x;
    if (idx >= 6656) return;
    if (idx < 3584) {
        const int h = idx / 224, r = idx % 224;
        const int es = r / 112, r2 = r % 112;
        const float p = es ? -1.f : 1.f;
        const int c = (r2 < 96) ? (r2 & 15) : (r2 - 96);
        const int e = c >> 2, a = c & 3;
        const int base = (e == 0 || e == 3) ? 0 : 8;
        const float se = (e == 0 || e == 1) ? 1.f : -1.f;
        float val = 0.f;
        for (int k = 0; k < 2; ++k) {
            const int i = a + base + 4 * k;
            const float beta = k ? se : 1.f;
            const int m = MT.mm[i];
            const float s = (float)MT.ms[i];
            const float sg = (float)MT.sig[m];
            float wm, wn;
            if (r2 < 96) {
                const int d = r2 >> 4;
                wm = W_in[d * 512 + h * 32 + m];
                wn = W_in[d * 512 + h * 32 + (m ^ 31)];
            } else {
                wm = b_in[h * 32 + m];
                wn = b_in[h * 32 + (m ^ 31)];
            }
            val += beta * s * (wm + p * sg * wn);
        }
        WP[idx] = val;
    } else {
        const int j = idx - 3584;
        const int h = j / 192, r = j % 192;
        const int es = r / 96, r2 = r % 96;
        const float p = es ? -1.f : 1.f;
        const int c = r2 / 6, d = r2 % 6;
        const int e = c >> 2, a = c & 3;
        const int base = (e == 0 || e == 3) ? 0 : 8;
        const float se = (e == 0 || e == 1) ? 1.f : -1.f;
        float val = 0.f;
        for (int k = 0; k < 2; ++k) {
            const int i = a + base + 4 * k;
            const float beta = k ? se : 1.f;
            const int m = MT.mm[i];
            const float s = (float)MT.ms[i];
            const float sg = (float)MT.sig[m];
            const float wm = W_out[(h * 32 + m) * 6 + d];
            const float wn = W_out[(h * 32 + (m ^ 31)) * 6 + d];
            val += 0.25f * beta * s * (wm + p * sg * wn);
        }
        WP[idx] = val;
    }
}

// U = matrix coords of delta_r in one eigenspace (+identity I on M11_0,M22_0)
__device__ __forceinline__ void build16(const float* __restrict__ Wsp,
                                        const float xv[6], float U[16]) {
#pragma unroll
    for (int c = 0; c < 16; ++c) U[c] = Wsp[96 + c];
#pragma unroll
    for (int d = 0; d < 6; ++d)
#pragma unroll
        for (int c = 0; c < 16; ++c)
            U[c] = fmaf(xv[d], Wsp[d * 16 + c], U[c]);
    U[0]  += 1.0f;   // +1 scalar blade = identity matrix
    U[12] += 1.0f;
}

// z += p (*) q, quaternion product via constexpr structure constants
__device__ __forceinline__ void hfma(float* __restrict__ z,
                                     const float* __restrict__ p,
                                     const float* __restrict__ q) {
#pragma unroll
    for (int a = 0; a < 4; ++a)
#pragma unroll
        for (int b = 0; b < 4; ++b)
            z[MT.qi[a][b]] = fmaf((float)MT.qs[a][b] * p[a], q[b], z[MT.qi[a][b]]);
}

// Z = U * X as 2x2 quaternion matrices (U left). 128 FMA.
__device__ __forceinline__ void gpm(float* __restrict__ Z,
                                    const float* __restrict__ U,
                                    const float* __restrict__ X) {
#pragma unroll
    for (int k = 0; k < 16; ++k) Z[k] = 0.f;
    hfma(Z + 0,  U + 0, X + 0);   hfma(Z + 0,  U + 4,  X + 8);
    hfma(Z + 4,  U + 0, X + 4);   hfma(Z + 4,  U + 4,  X + 12);
    hfma(Z + 8,  U + 8, X + 0);   hfma(Z + 8,  U + 12, X + 8);
    hfma(Z + 12, U + 8, X + 4);   hfma(Z + 12, U + 12, X + 12);
}

__device__ __forceinline__ float ssum32(const float* a, const float* b) {
    float s0 = 0.f, s1 = 0.f, s2 = 0.f, s3 = 0.f;
#pragma unroll
    for (int k = 0; k < 16; k += 4) {
        s0 = fmaf(a[k],     a[k],     s0); s1 = fmaf(a[k + 1], a[k + 1], s1);
        s2 = fmaf(a[k + 2], a[k + 2], s2); s3 = fmaf(a[k + 3], a[k + 3], s3);
        s0 = fmaf(b[k],     b[k],     s0); s1 = fmaf(b[k + 1], b[k + 1], s1);
        s2 = fmaf(b[k + 2], b[k + 2], s2); s3 = fmaf(b[k + 3], b[k + 3], s3);
    }
    return (s0 + s1) + (s2 + s3);   // |psi|^2_blades = 0.25 * ssum32
}

// Block blk: hg = blk&3, bn = blk>>2 (ONE chain per block). Waves w=0..3
// -> h = 4*hg + w. Lane sc = 0..63 = segment; L=4 steps each.
__global__ __launch_bounds__(256, 1) void k_fused(
        const float* __restrict__ x, const float* __restrict__ WP,
        float* __restrict__ WS4) {
    __shared__ float LP[4 * 4 * 64 * 6];   // [w][i][sc][d], 24 KB

    const int tid  = threadIdx.x;
    const int sc   = tid & 63;
    const int w    = __builtin_amdgcn_readfirstlane((int)(tid >> 6));
    const int hg   = blockIdx.x & 3;
    const int bn   = blockIdx.x >> 2;
    const int h    = 4 * hg + w;
    const int b = bn >> 4, n = bn & 15;
    const float* __restrict__ Wp0 = WP + h * 224;        // es+
    const float* __restrict__ Wp1 = WP + h * 224 + 112;  // es-
    const float* __restrict__ Op0 = WP + 3584 + h * 192;        // recon es+
    const float* __restrict__ Op1 = WP + 3584 + h * 192 + 96;   // recon es-

    // ---------- phase 1: segment product over t = sc*4 .. sc*4+3 ----------
    float Xp[16], Xm[16];
    {   // step 0: psi = u_0
        const int t = sc * 4;
        const float2* xp = (const float2*)(x + ((b * 256 + t) * 16 + n) * 6);
        float2 x01 = xp[0], x23 = xp[1], x45 = xp[2];
        const float xv[6] = {x01.x, x01.y, x23.x, x23.y, x45.x, x45.y};
        build16(Wp0, xv, Xp);
        build16(Wp1, xv, Xm);
    }
    for (int i = 1; i < 4; ++i) {
        const int t = sc * 4 + i;
        const float2* xp = (const float2*)(x + ((b * 256 + t) * 16 + n) * 6);
        float2 x01 = xp[0], x23 = xp[1], x45 = xp[2];
        const float xv[6] = {x01.x, x01.y, x23.x, x23.y, x45.x, x45.y};
        float U[16], Z[16];
        build16(Wp0, xv, U);
        gpm(Z, U, Xp);
#pragma unroll
        for (int k = 0; k < 16; ++k) Xp[k] = Z[k];
        build16(Wp1, xv, U);
        gpm(Z, U, Xm);
#pragma unroll
        for (int k = 0; k < 16; ++k) Xm[k] = Z[k];
    }
    {   // normalize once before the scan
        float rs = rsqrtf(0.25f * ssum32(Xp, Xm) + EPS);
#pragma unroll
        for (int k = 0; k < 16; ++k) { Xp[k] *= rs; Xm[k] *= rs; }
    }

    // ---------- phase 2: Kogge-Stone inclusive scan over sc (width 64) ----
#pragma unroll
    for (int k = 1; k < 64; k <<= 1) {
        float prp[16], prm[16];
#pragma unroll
        for (int j = 0; j < 16; ++j) {
            prp[j] = __shfl_up(Xp[j], k, 64);
            prm[j] = __shfl_up(Xm[j], k, 64);
        }
        if (sc >= k) {
            float Z[16];
            gpm(Z, Xp, prp);    // later range LEFT
#pragma unroll
            for (int m = 0; m < 16; ++m) Xp[m] = Z[m];
            gpm(Z, Xm, prm);
#pragma unroll
            for (int m = 0; m < 16; ++m) Xm[m] = Z[m];
        }
    }
    {   // single normalization of the inclusive prefix
        float rs = rsqrtf(0.25f * ssum32(Xp, Xm) + EPS);
#pragma unroll
        for (int j = 0; j < 16; ++j) { Xp[j] *= rs; Xm[j] *= rs; }
    }
    // exclusive shift by one
    float Rp[16], Rm[16];
#pragma unroll
    for (int j = 0; j < 16; ++j) {
        Rp[j] = __shfl_up(Xp[j], 1, 64);
        Rm[j] = __shfl_up(Xm[j], 1, 64);
    }
    if (sc == 0) {
#pragma unroll
        for (int j = 0; j < 16; ++j) { Rp[j] = 0.0f; Rm[j] = 0.0f; }
        Rp[0] = 1.0f; Rp[12] = 1.0f;   // identity matrix, both eigenspaces
        Rm[0] = 1.0f; Rm[12] = 1.0f;
    }

    // ---------- phase 3: apply interior + project -> LDS partials ----------
    for (int i = 0; i < 4; ++i) {
        const int t = sc * 4 + i;
        const float2* xp = (const float2*)(x + ((b * 256 + t) * 16 + n) * 6);
        float2 x01 = xp[0], x23 = xp[1], x45 = xp[2];
        const float xv[6] = {x01.x, x01.y, x23.x, x23.y, x45.x, x45.y};
        float U[16], Zp[16], Zm[16];
        build16(Wp0, xv, U);
        gpm(Zp, U, Rp);
        build16(Wp1, xv, U);
        gpm(Zm, U, Rm);
        float rs = rsqrtf(0.25f * ssum32(Zp, Zm) + EPS);
        float pd[6] = {0.f, 0.f, 0.f, 0.f, 0.f, 0.f};
#pragma unroll
        for (int c = 0; c < 16; ++c)
#pragma unroll
            for (int d = 0; d < 6; ++d) {
                pd[d] = fmaf(Zp[c], Op0[c * 6 + d], pd[d]);
                pd[d] = fmaf(Zm[c], Op1[c * 6 + d], pd[d]);
            }
#pragma unroll
        for (int k = 0; k < 16; ++k) { Rp[k] = Zp[k]; Rm[k] = Zm[k]; }
        float* lp = LP + ((w * 4 + i) * 64 + sc) * 6;
#pragma unroll
        for (int d = 0; d < 6; ++d) lp[d] = pd[d] * rs;
    }

    __syncthreads();

    // ---------- phase 4: reduce the block's 4 h, coalesced WS4 write ------
    // slot s = t*6+d; t = sc4*4 + i  ->  LP[w][i = t&3][sc4 = t>>2][d]
    float* outp = WS4 + (hg * 256 + bn) * 1536;
    for (int s = tid; s < 1536; s += 256) {
        const int d = s % 6, t = s / 6;
        const int li = ((t & 3) * 64 + (t >> 2)) * 6 + d;
        float acc = LP[0 * 1536 + li] + LP[1 * 1536 + li]
                  + LP[2 * 1536 + li] + LP[3 * 1536 + li];
        outp[s] = acc;
    }
}

// out[o] = x[o] + b_out[d] + sum_hg WS4[hg][bn][slot],  slot = t*6+d
__global__ __launch_bounds__(256, 1) void k_reduce(
        const float* __restrict__ x, const float* __restrict__ b_out,
        const float* __restrict__ WS4, float* __restrict__ out) {
    const int idx = blockIdx.x * 256 + threadIdx.x;  // 393216 total
    const int bn = idx / 1536, s = idx % 1536;
    const int d = s % 6, t = s / 6;
    const int b = bn >> 4, n = bn & 15;
    const int o = ((b * 256 + t) * 16 + n) * 6 + d;
    float acc = x[o] + b_out[d];
#pragma unroll
    for (int hg = 0; hg < 4; ++hg)
        acc += WS4[(hg * 256 + bn) * 1536 + s];
    out[o] = acc;
}

extern "C" void kernel_launch(void* const* d_in, const int* in_sizes, int n_in,
                              void* d_out, int out_size, void* d_ws, size_t ws_size,
                              hipStream_t stream) {
    (void)in_sizes; (void)n_in; (void)out_size; (void)ws_size;
    const float* x     = (const float*)d_in[0];  // [16,256,16,6]
    const float* W_in  = (const float*)d_in[1];  // [6,512]
    const float* b_in  = (const float*)d_in[2];  // [512]
    const float* W_out = (const float*)d_in[3];  // [512,6]
    const float* b_out = (const float*)d_in[4];  // [6]
    float* out = (float*)d_out;                  // [16,256,16,6]

    float* WP  = (float*)d_ws;                   // 6656 floats (26.6 KB)
    float* WS4 = (float*)((char*)d_ws + 32768);  // 4*256*1536 floats (6 MB)

    k_prep  <<<26,   256, 0, stream>>>(W_in, b_in, W_out, WP);
    k_fused <<<1024, 256, 0, stream>>>(x, WP, WS4);
    k_reduce<<<1536, 256, 0, stream>>>(x, b_out, WS4, out);
}